// Round 13
// baseline (2642.631 us; speedup 1.0000x reference)
//
#include <hip/hip_runtime.h>
#include <math.h>

// ---------------- constants (ViT-Base on 224x224) ----------------
static constexpr int kB   = 32;
static constexpr int kC   = 3;
static constexpr int kH   = 224;
static constexpr int kW   = 224;
static constexpr int kP   = 14;    // patches per side
static constexpr int kPS  = 16;    // patch size
static constexpr int kD   = 768;
static constexpr int kNH  = 12;
static constexpr int kDH  = 64;
static constexpr int kL   = 12;
static constexpr int kFF  = 3072;
static constexpr int kOUT = 1000;
static constexpr int kS   = 197;   // tokens
static constexpr int kTOK = kB * kS;    // 6304
static constexpr int kNP  = kP * kP;    // 196
static constexpr int kMP  = 6400;       // padded token rows (50*128)
static constexpr int kQKV = 3 * kD;     // 2304

typedef unsigned short u16;
typedef __attribute__((ext_vector_type(4))) float f32x4;
typedef __attribute__((ext_vector_type(8))) short bf16x8;

__device__ __forceinline__ u16 f2bf(float x) {
    unsigned u = __float_as_uint(x);
    return (u16)((u + 0x7FFFu + ((u >> 16) & 1u)) >> 16);   // RNE
}
__device__ __forceinline__ float bf2f(u16 x) {
    return __uint_as_float((unsigned)x << 16);
}
__device__ __forceinline__ void cp16_async(void* lds, const void* g) {
    __builtin_amdgcn_global_load_lds((const __attribute__((address_space(1))) unsigned*)g,
                                     (__attribute__((address_space(3))) unsigned*)lds,
                                     16, 0, 0);
}
// exact-gelu via Abramowitz-Stegun 7.1.26 erf (max abs err 1.5e-7; ~8 VALU + rcp + exp)
__device__ __forceinline__ float gelu_f(float v) {
    float z = v * 0.70710678118654752f;
    float s = fabsf(z);
    float t = 1.0f / (1.0f + 0.3275911f * s);
    float p = t * (0.254829592f + t * (-0.284496736f +
              t * (1.421413741f + t * (-1.453152027f + t * 1.061405429f))));
    float e = p * __expf(-s * s);
    float erfv = (z < 0.0f) ? (e - 1.0f) : (1.0f - e);
    return 0.5f * v * (1.0f + erfv);
}

// ---------------- positional encoding (float math, no double pow) ----------------
__global__ void vit_posenc(float* __restrict__ pos) {
    int idx = blockIdx.x * 256 + threadIdx.x;
    if (idx >= kS * kD) return;
    int s = idx / kD, d = idx % kD;
    int je = d & ~1;
    // 1/10000^(je/768) = exp(-je * ln(10000)/768)
    float ang = (float)s * __expf((float)je * (-9.210340371976184f / 768.0f));
    pos[idx] = (d & 1) ? cosf(ang) : sinf(ang);
}

// ---------------- im2col -> bf16 patches [6400][768], pad rows zero ----------------
__global__ void vit_im2col_bf16(const float* __restrict__ img, u16* __restrict__ patches) {
    long idx = (long)blockIdx.x * 256 + threadIdx.x;
    if (idx >= (long)kMP * kD) return;
    int col = (int)(idx % kD);
    long rp = idx / kD;
    if (rp >= (long)kB * kNP) { patches[idx] = 0; return; }
    int p = (int)(rp % kNP), b = (int)(rp / kNP);
    int c = col >> 8;
    int rem = col & 255;
    int i = rem >> 4, j = rem & 15;
    int py = p / kP, px = p % kP;
    patches[idx] = f2bf(img[(((long)b * kC + c) * kH + py * kPS + i) * kW + px * kPS + j]);
}

// ---------------- assemble x = concat(cls, tokens) + pos; pad rows zero ----------------
__global__ void vit_assemble(const float* __restrict__ tokens, const float* __restrict__ cls,
                             const float* __restrict__ pos, float* __restrict__ x) {
    long idx = (long)blockIdx.x * 256 + threadIdx.x;
    if (idx >= (long)kMP * kD) return;
    int d = (int)(idx % kD);
    long bs = idx / kD;
    if (bs >= kTOK) { x[idx] = 0.0f; return; }
    int s = (int)(bs % kS);
    long b = bs / kS;
    float v = (s == 0) ? cls[d] : tokens[((long)b * kNP + (s - 1)) * kD + d];
    x[idx] = v + pos[s * kD + d];
}

// ---------------- fp32 -> bf16 casts ----------------
__global__ void cast_bf16(const float* __restrict__ in, u16* __restrict__ out, long n4) {
    long i = (long)blockIdx.x * 256 + threadIdx.x;
    if (i >= n4) return;
    float4 v = *(const float4*)(in + i * 4);
    *(ushort4*)(out + i * 4) = make_ushort4(f2bf(v.x), f2bf(v.y), f2bf(v.z), f2bf(v.w));
}
// two sources, grid-stride (G11: cap grid, stride the rest)
__global__ void cast2_bf16(const float* __restrict__ in1, const float* __restrict__ in2,
                           u16* __restrict__ out1, u16* __restrict__ out2, long n4each) {
    const long stride = (long)gridDim.x * 256;
    for (long i = (long)blockIdx.x * 256 + threadIdx.x; i < 2 * n4each; i += stride) {
        const float* in = (i < n4each) ? in1 : in2;
        u16* out        = (i < n4each) ? out1 : out2;
        long j          = (i < n4each) ? i : i - n4each;
        float4 v = *(const float4*)(in + j * 4);
        *(ushort4*)(out + j * 4) = make_ushort4(f2bf(v.x), f2bf(v.y), f2bf(v.z), f2bf(v.w));
    }
}

__global__ void zero_u16(u16* __restrict__ p, long n) {
    long i = (long)blockIdx.x * 256 + threadIdx.x;
    if (i < n) p[i] = 0;
}

// ---------------- per-head QKV weights, ALL layers: [L][12][192][64] bf16 + bias [L][12][192] ----------------
__global__ void build_whb_all(const float* __restrict__ Wq, const float* __restrict__ Wk,
                              const float* __restrict__ Wv, const float* __restrict__ bq,
                              const float* __restrict__ bk, const float* __restrict__ bv,
                              u16* __restrict__ Wh, float* __restrict__ bh) {
    int idx = blockIdx.x * 256 + threadIdx.x;
    if (idx >= kL * kNH * 192 * 64) return;
    int d  = idx & 63;
    int r  = (idx >> 6) % 192;
    int lh = (idx >> 6) / 192;         // l*12 + h
    int sec = r >> 6, e = r & 63;
    const float* W = (sec == 0) ? Wq : (sec == 1) ? Wk : Wv;
    Wh[idx] = f2bf(W[((long)lh * 64 + e) * 64 + d]);
    if (d == 0) {
        const float* bs = (sec == 0) ? bq : (sec == 1) ? bk : bv;
        bh[lh * 192 + r] = bs[lh * 64 + e];
    }
}

// ---------------- layernorm: fp32 in -> bf16 out, one block per token ----------------
__global__ __launch_bounds__(256) void vit_ln(const float* __restrict__ x,
                                              const float* __restrict__ g,
                                              const float* __restrict__ b,
                                              u16* __restrict__ out) {
    long t = blockIdx.x;
    const float* xr = x + t * kD;
    int tid = threadIdx.x;
    float v0 = xr[tid], v1 = xr[tid + 256], v2 = xr[tid + 512];
    float s  = v0 + v1 + v2;
    float sq = v0 * v0 + v1 * v1 + v2 * v2;
    #pragma unroll
    for (int o = 32; o; o >>= 1) { s += __shfl_xor(s, o); sq += __shfl_xor(sq, o); }
    __shared__ float red[8];
    int wid = tid >> 6, lane = tid & 63;
    if (lane == 0) { red[wid] = s; red[4 + wid] = sq; }
    __syncthreads();
    s  = red[0] + red[1] + red[2] + red[3];
    sq = red[4] + red[5] + red[6] + red[7];
    float mu  = s * (1.0f / kD);
    float var = sq * (1.0f / kD) - mu * mu;
    float rs  = rsqrtf(var + 1e-5f);
    u16* orow = out + t * kD;
    orow[tid]       = f2bf((v0 - mu) * rs * g[tid]       + b[tid]);
    orow[tid + 256] = f2bf((v1 - mu) * rs * g[tid + 256] + b[tid + 256]);
    orow[tid + 512] = f2bf((v2 - mu) * rs * g[tid + 512] + b[tid + 512]);
}

// ---------------- bf16 MFMA GEMM, 128x128 tile (R5-proven loop: ~71us FF) ----------------
// BK=32, 3-deep LDS ring, counted vmcnt(4), TWO raw barriers/step, stage issued
// between fragment ds_reads and MFMAs. Source-side XOR chunk swizzle (0 conflicts).
// EPI: 0 bias->f32, 1 bias+gelu->bf16, 2 bias+residual(X)->f32, 3 bias->bf16
template <int EPI>
__global__ __launch_bounds__(256) void mm_bt(const u16* __restrict__ A, int lda,
                                             const u16* __restrict__ B, int ldb,
                                             const float* __restrict__ bias,
                                             const float* X, void* Cout, int ldc, int K) {
    __shared__ __align__(16) u16 As[3][4096];
    __shared__ __align__(16) u16 Bs[3][4096];

    const int gx = gridDim.x, gy = gridDim.y;
    const int nwg = gx * gy;
    const int disp = blockIdx.y * gx + blockIdx.x;
    const int q8 = nwg >> 3, r8 = nwg & 7;
    const int xcd = disp & 7, lot = disp >> 3;
    const int work = (xcd < r8 ? xcd * (q8 + 1) : r8 * (q8 + 1) + (xcd - r8) * q8) + lot;
    const int row0 = (work / gy) << 7;
    const int col0 = (work % gy) << 7;

    const int tid  = threadIdx.x;
    const int lane = tid & 63;
    const int wm = ((tid >> 6) >> 1) << 6;   // wave row 0/64
    const int wn = ((tid >> 6) & 1) << 6;    // wave col 0/64
    const int lr = lane & 15, lhi = lane >> 4;

    const int srow = tid >> 2;
    const int sch  = (((tid & 3) ^ ((srow >> 1) & 3)) << 3);
    const u16* Ag = A + (long)(row0 + srow) * lda + sch;
    const u16* Bg = B + (long)(col0 + srow) * ldb + sch;
    const long Astep = 64L * lda, Bstep = 64L * ldb;
    const int ldst = tid << 3;

    auto stage = [&](int buf, int k0) {
        cp16_async(&As[buf][ldst],        Ag + k0);
        cp16_async(&As[buf][ldst + 2048], Ag + Astep + k0);
        cp16_async(&Bs[buf][ldst],        Bg + k0);
        cp16_async(&Bs[buf][ldst + 2048], Bg + Bstep + k0);
    };
    stage(0, 0);
    stage(1, 32);

    f32x4 acc[4][4] = {};
    const int nk = K >> 5;
    const int rch = (lhi ^ ((lr >> 1) & 3)) << 3;
    int cur = 0;
    for (int t = 0; t < nk; t++) {
        if (t + 1 < nk) asm volatile("s_waitcnt vmcnt(4)" ::: "memory");
        else            asm volatile("s_waitcnt vmcnt(0)" ::: "memory");
        __builtin_amdgcn_sched_barrier(0);
        __builtin_amdgcn_s_barrier();
        bf16x8 af[4], bfr[4];
        #pragma unroll
        for (int m = 0; m < 4; m++)
            af[m] = *(const bf16x8*)&As[cur][(wm + (m << 4) + lr) * 32 + rch];
        #pragma unroll
        for (int n = 0; n < 4; n++)
            bfr[n] = *(const bf16x8*)&Bs[cur][(wn + (n << 4) + lr) * 32 + rch];
        if (t + 2 < nk) {
            int nb = cur + 2; if (nb >= 3) nb -= 3;
            stage(nb, (t + 2) << 5);
        }
        #pragma unroll
        for (int m = 0; m < 4; m++)
            #pragma unroll
            for (int n = 0; n < 4; n++)
                acc[m][n] = __builtin_amdgcn_mfma_f32_16x16x32_bf16(af[m], bfr[n], acc[m][n], 0, 0, 0);
        __builtin_amdgcn_s_barrier();
        cur = (cur + 1 == 3) ? 0 : cur + 1;
    }

    const int r0 = wm + (lhi << 2);
    const int cb = wn + lr;
    #pragma unroll
    for (int n = 0; n < 4; n++) {
        const int cc = col0 + cb + (n << 4);
        const float bv = bias[cc];
        #pragma unroll
        for (int m = 0; m < 4; m++) {
            #pragma unroll
            for (int r = 0; r < 4; r++) {
                const long idx = (long)(row0 + r0 + (m << 4) + r) * ldc + cc;
                float v = acc[m][n][r] + bv;
                if (EPI == 1) {
                    ((u16*)Cout)[idx] = f2bf(gelu_f(v));
                } else if (EPI == 2) {
                    ((float*)Cout)[idx] = v + X[idx];
                } else if (EPI == 3) {
                    ((u16*)Cout)[idx] = f2bf(v);
                } else {
                    ((float*)Cout)[idx] = v;
                }
            }
        }
    }
}

// ---------------- bf16 MFMA GEMM, 128x256 tile, 8 waves (FF1) ----------------
// Same R5-proven schedule (ring-3, counted vmcnt(3), 2 barriers, stage between
// reads and MFMAs, XOR swizzle) but 8 waves/block and 72KB LDS -> 2 blocks/CU
// = 16 waves/CU (vs 12): better latency hiding, same per-MFMA LDS traffic.
template <int EPI>
__global__ __launch_bounds__(512, 4) void mm_bt2(const u16* __restrict__ A, int lda,
                                                 const u16* __restrict__ B, int ldb,
                                                 const float* __restrict__ bias,
                                                 const float* X, void* Cout, int ldc, int K) {
    __shared__ __align__(16) u16 As[3][4096];   // 128 x 32
    __shared__ __align__(16) u16 Bs[3][8192];   // 256 x 32

    const int gx = gridDim.x, gy = gridDim.y;
    const int nwg = gx * gy;
    const int disp = blockIdx.y * gx + blockIdx.x;
    const int q8 = nwg >> 3, r8 = nwg & 7;
    const int xcd = disp & 7, lot = disp >> 3;
    const int work = (xcd < r8 ? xcd * (q8 + 1) : r8 * (q8 + 1) + (xcd - r8) * q8) + lot;
    const int row0 = (work / gy) << 7;    // 128-row tiles
    const int col0 = (work % gy) << 8;    // 256-col tiles

    const int tid  = threadIdx.x;
    const int lane = tid & 63;
    const int wid  = tid >> 6;             // 0..7
    const int wm = (wid >> 2) << 6;        // 0 / 64
    const int wn = (wid & 3) << 6;         // 0,64,128,192
    const int lr = lane & 15, lhi = lane >> 4;

    // staging: A rows tid>>2 (1 load); B rows tid>>2 and +128 (2 loads).
    // (row+128)>>1 & 3 == (row>>1) & 3, so one swizzle term covers both.
    const int srow = tid >> 2;
    const int sch  = (((tid & 3) ^ ((srow >> 1) & 3)) << 3);
    const u16* Ag = A + (long)(row0 + srow) * lda + sch;
    const u16* Bg = B + (long)(col0 + srow) * ldb + sch;
    const long Bstep = 128L * ldb;
    const int ldst = tid << 3;

    auto stage = [&](int buf, int k0) {    // 3 vm ops
        cp16_async(&As[buf][ldst],        Ag + k0);
        cp16_async(&Bs[buf][ldst],        Bg + k0);
        cp16_async(&Bs[buf][ldst + 4096], Bg + Bstep + k0);
    };
    stage(0, 0);
    stage(1, 32);

    f32x4 acc[4][4] = {};
    const int nk = K >> 5;
    const int rch = (lhi ^ ((lr >> 1) & 3)) << 3;
    int cur = 0;
    for (int t = 0; t < nk; t++) {
        if (t + 1 < nk) asm volatile("s_waitcnt vmcnt(3)" ::: "memory");
        else            asm volatile("s_waitcnt vmcnt(0)" ::: "memory");
        __builtin_amdgcn_sched_barrier(0);
        __builtin_amdgcn_s_barrier();
        bf16x8 af[4], bfr[4];
        #pragma unroll
        for (int m = 0; m < 4; m++)
            af[m] = *(const bf16x8*)&As[cur][(wm + (m << 4) + lr) * 32 + rch];
        #pragma unroll
        for (int n = 0; n < 4; n++)
            bfr[n] = *(const bf16x8*)&Bs[cur][(wn + (n << 4) + lr) * 32 + rch];
        if (t + 2 < nk) {
            int nb = cur + 2; if (nb >= 3) nb -= 3;
            stage(nb, (t + 2) << 5);
        }
        #pragma unroll
        for (int m = 0; m < 4; m++)
            #pragma unroll
            for (int n = 0; n < 4; n++)
                acc[m][n] = __builtin_amdgcn_mfma_f32_16x16x32_bf16(af[m], bfr[n], acc[m][n], 0, 0, 0);
        __builtin_amdgcn_s_barrier();
        cur = (cur + 1 == 3) ? 0 : cur + 1;
    }

    const int r0 = wm + (lhi << 2);
    const int cb = wn + lr;
    #pragma unroll
    for (int n = 0; n < 4; n++) {
        const int cc = col0 + cb + (n << 4);
        const float bv = bias[cc];
        #pragma unroll
        for (int m = 0; m < 4; m++) {
            #pragma unroll
            for (int r = 0; r < 4; r++) {
                const long idx = (long)(row0 + r0 + (m << 4) + r) * ldc + cc;
                float v = acc[m][n][r] + bv;
                if (EPI == 1) {
                    ((u16*)Cout)[idx] = f2bf(gelu_f(v));
                } else if (EPI == 2) {
                    ((float*)Cout)[idx] = v + X[idx];
                } else if (EPI == 3) {
                    ((u16*)Cout)[idx] = f2bf(v);
                } else {
                    ((float*)Cout)[idx] = v;
                }
            }
        }
    }
}

// ---------------- per-head block-diag QKV: qkv = h_head @ Wh^T + bh ----------------
__global__ __launch_bounds__(256) void mm_qkv(const u16* __restrict__ hbm,
                                              const u16* __restrict__ Wh,
                                              const float* __restrict__ bh,
                                              u16* __restrict__ qkv) {
    const int h = blockIdx.y;
    const int row0 = blockIdx.x << 6;
    const int tid = threadIdx.x, lane = tid & 63, wave = tid >> 6;
    const int l15 = lane & 15, lhi = lane >> 4;
    const u16* Ab = hbm + h * kDH + (lhi << 3);
    const u16* Bb = Wh + (long)h * 192 * 64 + (lhi << 3);

    bf16x8 af[4][2];
    #pragma unroll
    for (int m = 0; m < 4; m++) {
        const u16* ap = Ab + (long)(row0 + (m << 4) + l15) * kD;
        af[m][0] = *(const bf16x8*)ap;
        af[m][1] = *(const bf16x8*)(ap + 32);
    }
    bf16x8 bfr[3][2];
    #pragma unroll
    for (int n = 0; n < 3; n++) {
        const u16* bp = Bb + (long)(wave * 48 + (n << 4) + l15) * 64;
        bfr[n][0] = *(const bf16x8*)bp;
        bfr[n][1] = *(const bf16x8*)(bp + 32);
    }
    f32x4 acc[4][3] = {};
    __builtin_amdgcn_s_setprio(1);
    #pragma unroll
    for (int m = 0; m < 4; m++)
        #pragma unroll
        for (int n = 0; n < 3; n++) {
            acc[m][n] = __builtin_amdgcn_mfma_f32_16x16x32_bf16(af[m][0], bfr[n][0], acc[m][n], 0, 0, 0);
            acc[m][n] = __builtin_amdgcn_mfma_f32_16x16x32_bf16(af[m][1], bfr[n][1], acc[m][n], 0, 0, 0);
        }
    __builtin_amdgcn_s_setprio(0);
    #pragma unroll
    for (int n = 0; n < 3; n++) {
        const int c = wave * 48 + (n << 4) + l15;        // [0,192)
        const int sec = c >> 6, e = c & 63;
        const float bv = bh[h * 192 + c];
        const long gcol = (long)sec * kD + h * kDH + e;
        #pragma unroll
        for (int m = 0; m < 4; m++)
            #pragma unroll
            for (int i = 0; i < 4; i++) {
                const int r = row0 + (m << 4) + (lhi << 2) + i;
                qkv[(long)r * kQKV + gcol] = f2bf(acc[m][n][i] + bv);
            }
    }
}

// ---------------- fused attention: scores+softmax+PV, bf16 MFMA ----------------
__global__ __launch_bounds__(256) void vit_attn_fused(const u16* __restrict__ qkv,
                                                      float* __restrict__ x) {
    constexpr int SP = 224;
    constexpr int NT = 13;
    constexpr int LDP = 232;
    __shared__ u16 Plds[64][LDP];
    __shared__ u16 Vt[64][LDP];

    const int z = blockIdx.y, qt = blockIdx.x;
    const int b = z / kNH, h = z % kNH;
    const u16* base = qkv + (long)b * kS * kQKV;
    const u16* Qg = base + h * kDH;
    const u16* Kg = base + kD + h * kDH;
    const u16* Vg = base + 2 * kD + h * kDH;
    const int tid = threadIdx.x, lane = tid & 63, wave = tid >> 6;
    const int l15 = lane & 15, lhi = lane >> 4;

    for (int i = tid; i < (SP * kDH) / 4; i += 256) {
        int s  = i >> 4;
        int d0 = (i & 15) << 2;
        ushort4 v = *(const ushort4*)(Vg + (long)s * kQKV + d0);
        Vt[d0 + 0][s] = v.x; Vt[d0 + 1][s] = v.y;
        Vt[d0 + 2][s] = v.z; Vt[d0 + 3][s] = v.w;
    }

    const int qrow = (qt << 6) + (wave << 4) + l15;
    const u16* qrp = Qg + (long)qrow * kQKV + (lhi << 3);
    const bf16x8 qf0 = *(const bf16x8*)(qrp);
    const bf16x8 qf1 = *(const bf16x8*)(qrp + 32);

    f32x4 sc[NT];
    const u16* krp = Kg + (long)l15 * kQKV + (lhi << 3);
    __builtin_amdgcn_s_setprio(1);
    #pragma unroll
    for (int t = 0; t < NT; t++) {
        const u16* kp = krp + (long)(t << 4) * kQKV;
        bf16x8 kb0 = *(const bf16x8*)(kp);
        bf16x8 kb1 = *(const bf16x8*)(kp + 32);
        f32x4 a = {0.0f, 0.0f, 0.0f, 0.0f};
        a = __builtin_amdgcn_mfma_f32_16x16x32_bf16(qf0, kb0, a, 0, 0, 0);
        a = __builtin_amdgcn_mfma_f32_16x16x32_bf16(qf1, kb1, a, 0, 0, 0);
        sc[t] = a;
    }
    __builtin_amdgcn_s_setprio(0);

    float mx[4] = {-1e30f, -1e30f, -1e30f, -1e30f};
    #pragma unroll
    for (int t = 0; t < NT; t++) {
        const int c = (t << 4) + l15;
        #pragma unroll
        for (int q = 0; q < 4; q++) {
            float v = (c < kS) ? sc[t][q] * 0.125f : -1e30f;
            sc[t][q] = v;
            mx[q] = fmaxf(mx[q], v);
        }
    }
    #pragma unroll
    for (int o = 1; o < 16; o <<= 1)
        #pragma unroll
        for (int q = 0; q < 4; q++) mx[q] = fmaxf(mx[q], __shfl_xor(mx[q], o));
    float sum[4] = {0.0f, 0.0f, 0.0f, 0.0f};
    #pragma unroll
    for (int t = 0; t < NT; t++)
        #pragma unroll
        for (int q = 0; q < 4; q++) {
            float e = __expf(sc[t][q] - mx[q]);
            sc[t][q] = e;
            sum[q] += e;
        }
    #pragma unroll
    for (int o = 1; o < 16; o <<= 1)
        #pragma unroll
        for (int q = 0; q < 4; q++) sum[q] += __shfl_xor(sum[q], o);

    const int prow = (wave << 4) + (lhi << 2);
    #pragma unroll
    for (int t = 0; t < NT; t++)
        #pragma unroll
        for (int q = 0; q < 4; q++)
            Plds[prow + q][(t << 4) + l15] = f2bf(sc[t][q]);
    #pragma unroll
    for (int q = 0; q < 4; q++)
        Plds[prow + q][208 + l15] = 0;
    __syncthreads();

    f32x4 oacc[4] = {};
    const int arow = (wave << 4) + l15;
    const int koff = lhi << 3;
    __builtin_amdgcn_s_setprio(1);
    #pragma unroll
    for (int ks = 0; ks < 7; ks++) {
        bf16x8 pa = *(const bf16x8*)&Plds[arow][ks * 32 + koff];
        #pragma unroll
        for (int n = 0; n < 4; n++) {
            bf16x8 vb = *(const bf16x8*)&Vt[(n << 4) + l15][ks * 32 + koff];
            oacc[n] = __builtin_amdgcn_mfma_f32_16x16x32_bf16(pa, vb, oacc[n], 0, 0, 0);
        }
    }
    __builtin_amdgcn_s_setprio(0);

    const int orow0 = (qt << 6) + (wave << 4) + (lhi << 2);
    #pragma unroll
    for (int q = 0; q < 4; q++) {
        const int r = orow0 + q;
        if (r >= kS) continue;
        const float rinv = 1.0f / sum[q];
        float* xp = x + ((long)b * kS + r) * kD + h * kDH + l15;
        #pragma unroll
        for (int n = 0; n < 4; n++)
            xp[n << 4] += oacc[n][q] * rinv;
    }
}

// ---------------- fp32 GEMM (kept for tiny logits GEMM) ----------------
template <int ACT, int RES>
__global__ __launch_bounds__(256) void vit_gemm(const float* __restrict__ A, long lda, long sAz,
                                                const float* __restrict__ B, long ldb, long sBz,
                                                const float* __restrict__ bias, long sbz,
                                                const float* __restrict__ R,
                                                float* __restrict__ C, long ldc, long sCz,
                                                int M, int N, int K) {
    __shared__ __align__(16) float As[16][64];
    __shared__ __align__(16) float Bs[16][64];
    long z = blockIdx.z;
    A += z * sAz;  B += z * sBz;  C += z * sCz;
    if (bias) bias += z * sbz;
    const float* Rp = nullptr;
    if (RES) Rp = R + z * sCz;

    int row0 = blockIdx.x * 64, col0 = blockIdx.y * 64;
    int tid = threadIdx.x;
    int lr = tid >> 2, lk = (tid & 3) << 2;
    int tm = tid >> 4, tn = tid & 15;
    float acc[4][4] = {};

    for (int k0 = 0; k0 < K; k0 += 16) {
        float4 a = {0, 0, 0, 0}, bb = {0, 0, 0, 0};
        int gr = row0 + lr;
        if (gr < M) a = *(const float4*)(A + (long)gr * lda + k0 + lk);
        int gc = col0 + lr;
        if (gc < N) bb = *(const float4*)(B + (long)gc * ldb + k0 + lk);
        __syncthreads();
        As[lk + 0][lr] = a.x;  As[lk + 1][lr] = a.y;  As[lk + 2][lr] = a.z;  As[lk + 3][lr] = a.w;
        Bs[lk + 0][lr] = bb.x; Bs[lk + 1][lr] = bb.y; Bs[lk + 2][lr] = bb.z; Bs[lk + 3][lr] = bb.w;
        __syncthreads();
        #pragma unroll
        for (int k = 0; k < 16; k++) {
            const float4 av = *reinterpret_cast<const float4*>(&As[k][tm << 2]);
            const float4 bv = *reinterpret_cast<const float4*>(&Bs[k][tn << 2]);
            float aa[4] = {av.x, av.y, av.z, av.w};
            float bw[4] = {bv.x, bv.y, bv.z, bv.w};
            #pragma unroll
            for (int i = 0; i < 4; i++)
                #pragma unroll
                for (int j = 0; j < 4; j++)
                    acc[i][j] = fmaf(aa[i], bw[j], acc[i][j]);
        }
    }
    #pragma unroll
    for (int i = 0; i < 4; i++) {
        int r = row0 + (tm << 2) + i;
        if (r >= M) continue;
        #pragma unroll
        for (int j = 0; j < 4; j++) {
            int c = col0 + (tn << 2) + j;
            if (c >= N) continue;
            float v = acc[i][j];
            if (bias) v += bias[c];
            if (ACT == 1) v = gelu_f(v);
            if (RES) v += Rp[(long)r * ldc + c];
            C[(long)r * ldc + c] = v;
        }
    }
}

// ---------------- final softmax over 1000 logits ----------------
__global__ __launch_bounds__(256) void vit_smout(const float* __restrict__ logits,
                                                 float* __restrict__ out) {
    int b = blockIdx.x;
    const float* p = logits + (long)b * kOUT;
    int tid = threadIdx.x;
    float v[4];
    float mx = -1e30f;
    #pragma unroll
    for (int i = 0; i < 4; i++) {
        int c = tid + (i << 8);
        v[i] = (c < kOUT) ? p[c] : -1e30f;
        mx = fmaxf(mx, v[i]);
    }
    #pragma unroll
    for (int o = 32; o; o >>= 1) mx = fmaxf(mx, __shfl_xor(mx, o));
    __shared__ float red[8];
    int wid = tid >> 6, lane = tid & 63;
    if (lane == 0) red[wid] = mx;
    __syncthreads();
    mx = fmaxf(fmaxf(red[0], red[1]), fmaxf(red[2], red[3]));
    float sum = 0.0f;
    #pragma unroll
    for (int i = 0; i < 4; i++) {
        int c = tid + (i << 8);
        if (c < kOUT) { v[i] = expf(v[i] - mx); sum += v[i]; }
    }
    #pragma unroll
    for (int o = 32; o; o >>= 1) sum += __shfl_xor(sum, o);
    __syncthreads();
    if (lane == 0) red[4 + wid] = sum;
    __syncthreads();
    sum = red[4] + red[5] + red[6] + red[7];
    float inv = 1.0f / sum;
    #pragma unroll
    for (int i = 0; i < 4; i++) {
        int c = tid + (i << 8);
        if (c < kOUT) out[(long)b * kOUT + c] = v[i] * inv;
    }
}

// ---------------- host driver ----------------
extern "C" void kernel_launch(void* const* d_in, const int* in_sizes, int n_in,
                              void* d_out, int out_size, void* d_ws, size_t ws_size,
                              hipStream_t stream) {
    (void)in_sizes; (void)n_in; (void)out_size;
    const float* images  = (const float*)d_in[0];
    const float* W_patch = (const float*)d_in[1];
    const float* b_patch = (const float*)d_in[2];
    const float* cls     = (const float*)d_in[3];
    const float* ln1_g   = (const float*)d_in[4];
    const float* ln1_b   = (const float*)d_in[5];
    const float* Wq      = (const float*)d_in[6];
    const float* bq      = (const float*)d_in[7];
    const float* Wk      = (const float*)d_in[8];
    const float* bk      = (const float*)d_in[9];
    const float* Wv      = (const float*)d_in[10];
    const float* bv      = (const float*)d_in[11];
    const float* ln2_g   = (const float*)d_in[12];
    const float* ln2_b   = (const float*)d_in[13];
    const float* W1      = (const float*)d_in[14];
    const float* b1      = (const float*)d_in[15];
    const float* W2      = (const float*)d_in[16];
    const float* b2      = (const float*)d_in[17];
    const float* Wo      = (const float*)d_in[18];
    const float* bo      = (const float*)d_in[19];

    char* wsB = (char*)d_ws;
    auto alloc = [&](size_t bytes) { char* p = wsB; wsB += (bytes + 255) & ~(size_t)255; return p; };
    float* pos    = (float*)alloc((size_t)kS * kD * 4);
    float* x      = (float*)alloc((size_t)kMP * kD * 4);
    u16*   hb     = (u16*)  alloc((size_t)kMP * kD * 2);
    u16*   qkvb   = (u16*)  alloc((size_t)kMP * kQKV * 2);
    u16*   ff1b   = (u16*)  alloc((size_t)kMP * kFF * 2);
    u16*   Whb    = (u16*)  alloc((size_t)kL * kNH * 192 * 64 * 2);  // all layers
    u16*   Wpb    = (u16*)  alloc((size_t)kD * kD * 2);
    float* bhb    = (float*)alloc((size_t)kL * kNH * 192 * 4);
    float* logits = (float*)alloc((size_t)kB * kOUT * 4);

    // W1/W2 bf16: hoist all layers into ws if it fits, else per-layer double-use buffer
    const size_t perW  = (size_t)kFF * kD;                 // elems per W matrix
    const size_t used  = (size_t)(wsB - (char*)d_ws);
    const bool   hoist = ws_size >= used + 2 * kL * perW * 2 + (1u << 20);
    u16* W12b = (u16*)alloc(hoist ? 2 * kL * perW * 2 : 2 * perW * 2);

    float* tokens   = (float*)qkvb;   // reuse (pre-loop only)
    u16*   patchesb = ff1b;           // reuse (pre-loop only)

    // ---- pre-loop ----
    vit_posenc<<<(kS * kD + 255) / 256, 256, 0, stream>>>(pos);
    vit_im2col_bf16<<<(int)(((long)kMP * kD) / 256), 256, 0, stream>>>(images, patchesb);
    cast_bf16<<<(kD * kD / 4 + 255) / 256, 256, 0, stream>>>(W_patch, Wpb, (long)kD * kD / 4);
    build_whb_all<<<(kL * kNH * 192 * 64 + 255) / 256, 256, 0, stream>>>(
        Wq, Wk, Wv, bq, bk, bv, Whb, bhb);
    zero_u16<<<(96 * kD + 255) / 256, 256, 0, stream>>>(hb + (long)kTOK * kD, 96L * kD);
    if (hoist)   // all 12 layers' W1 then all W2, one grid-stride dispatch
        cast2_bf16<<<2048, 256, 0, stream>>>(
            W1, W2, W12b, W12b + kL * perW, (long)kL * perW / 4);
    mm_bt<0><<<dim3(kMP / 128, kD / 128), 256, 0, stream>>>(
        patchesb, kD, Wpb, kD, b_patch, nullptr, tokens, kD, kD);
    vit_assemble<<<(int)(((long)kMP * kD) / 256), 256, 0, stream>>>(tokens, cls, pos, x);

    for (int l = 0; l < kL; l++) {
        u16* W1l = hoist ? (W12b + (size_t)l * perW)            : W12b;
        u16* W2l = hoist ? (W12b + (size_t)(kL + l) * perW)     : W12b + perW;
        if (!hoist)
            cast2_bf16<<<2048, 256, 0, stream>>>(
                W1 + (size_t)l * perW, W2 + (size_t)l * perW, W1l, W2l, (long)perW / 4);

        vit_ln<<<kTOK, 256, 0, stream>>>(x, ln1_g + (long)l * kD, ln1_b + (long)l * kD, hb);
        mm_qkv<<<dim3(kMP / 64, kNH), 256, 0, stream>>>(
            hb, Whb + (long)l * kNH * 192 * 64, bhb + (long)l * kNH * 192, qkvb);

        vit_attn_fused<<<dim3(4, kB * kNH), 256, 0, stream>>>(qkvb, x);

        vit_ln<<<kTOK, 256, 0, stream>>>(x, ln2_g + (long)l * kD, ln2_b + (long)l * kD, hb);
        // ff1 = gelu(h @ W1^T + b1): 128x256 8-wave tile, grid 50x12=600
        mm_bt2<1><<<dim3(kMP / 128, kFF / 256), 512, 0, stream>>>(
            hb, kD, W1l, kD, b1 + (long)l * kFF, nullptr, ff1b, kFF, kD);
        // x = x + ff1 @ W2^T + b2: 128^2 (N=768 too narrow for 256-col tiles)
        mm_bt<2><<<dim3(kMP / 128, kD / 128), 256, 0, stream>>>(
            ff1b, kFF, W2l, kFF, b2 + (long)l * kD, x, x, kD, kFF);
    }

    vit_gemm<0, 0><<<dim3(1, 16, 1), 256, 0, stream>>>(
        x, (long)kS * kD, 0, Wo, kD, 0, bo, 0, nullptr,
        logits, kOUT, 0, kB, kOUT, kD);
    vit_smout<<<kB, 256, 0, stream>>>(logits, (float*)d_out);
}

// Round 14
// 2512.135 us; speedup vs baseline: 1.0519x; 1.0519x over previous
//
#include <hip/hip_runtime.h>
#include <math.h>

// ---------------- constants (ViT-Base on 224x224) ----------------
static constexpr int kB   = 32;
static constexpr int kC   = 3;
static constexpr int kH   = 224;
static constexpr int kW   = 224;
static constexpr int kP   = 14;    // patches per side
static constexpr int kPS  = 16;    // patch size
static constexpr int kD   = 768;
static constexpr int kNH  = 12;
static constexpr int kDH  = 64;
static constexpr int kL   = 12;
static constexpr int kFF  = 3072;
static constexpr int kOUT = 1000;
static constexpr int kS   = 197;   // tokens
static constexpr int kTOK = kB * kS;    // 6304
static constexpr int kNP  = kP * kP;    // 196
static constexpr int kMP  = 6400;       // padded token rows (50*128)
static constexpr int kQKV = 3 * kD;     // 2304

typedef unsigned short u16;
typedef __attribute__((ext_vector_type(4))) float f32x4;
typedef __attribute__((ext_vector_type(8))) short bf16x8;

__device__ __forceinline__ u16 f2bf(float x) {
    unsigned u = __float_as_uint(x);
    return (u16)((u + 0x7FFFu + ((u >> 16) & 1u)) >> 16);   // RNE
}
__device__ __forceinline__ float bf2f(u16 x) {
    return __uint_as_float((unsigned)x << 16);
}
__device__ __forceinline__ void cp16_async(void* lds, const void* g) {
    __builtin_amdgcn_global_load_lds((const __attribute__((address_space(1))) unsigned*)g,
                                     (__attribute__((address_space(3))) unsigned*)lds,
                                     16, 0, 0);
}
// exact-gelu via Abramowitz-Stegun 7.1.26 erf (max abs err 1.5e-7; ~8 VALU + rcp + exp)
__device__ __forceinline__ float gelu_f(float v) {
    float z = v * 0.70710678118654752f;
    float s = fabsf(z);
    float t = 1.0f / (1.0f + 0.3275911f * s);
    float p = t * (0.254829592f + t * (-0.284496736f +
              t * (1.421413741f + t * (-1.453152027f + t * 1.061405429f))));
    float e = p * __expf(-s * s);
    float erfv = (z < 0.0f) ? (e - 1.0f) : (1.0f - e);
    return 0.5f * v * (1.0f + erfv);
}

// ---------------- positional encoding (float math) ----------------
__global__ void vit_posenc(float* __restrict__ pos) {
    int idx = blockIdx.x * 256 + threadIdx.x;
    if (idx >= kS * kD) return;
    int s = idx / kD, d = idx % kD;
    int je = d & ~1;
    float ang = (float)s * __expf((float)je * (-9.210340371976184f / 768.0f));
    pos[idx] = (d & 1) ? cosf(ang) : sinf(ang);
}

// ---------------- im2col -> bf16 patches [6400][768], pad rows zero ----------------
__global__ void vit_im2col_bf16(const float* __restrict__ img, u16* __restrict__ patches) {
    long idx = (long)blockIdx.x * 256 + threadIdx.x;
    if (idx >= (long)kMP * kD) return;
    int col = (int)(idx % kD);
    long rp = idx / kD;
    if (rp >= (long)kB * kNP) { patches[idx] = 0; return; }
    int p = (int)(rp % kNP), b = (int)(rp / kNP);
    int c = col >> 8;
    int rem = col & 255;
    int i = rem >> 4, j = rem & 15;
    int py = p / kP, px = p % kP;
    patches[idx] = f2bf(img[(((long)b * kC + c) * kH + py * kPS + i) * kW + px * kPS + j]);
}

// ---------------- assemble x = concat(cls, tokens) + pos; pad rows zero ----------------
__global__ void vit_assemble(const float* __restrict__ tokens, const float* __restrict__ cls,
                             const float* __restrict__ pos, float* __restrict__ x) {
    long idx = (long)blockIdx.x * 256 + threadIdx.x;
    if (idx >= (long)kMP * kD) return;
    int d = (int)(idx % kD);
    long bs = idx / kD;
    if (bs >= kTOK) { x[idx] = 0.0f; return; }
    int s = (int)(bs % kS);
    long b = bs / kS;
    float v = (s == 0) ? cls[d] : tokens[((long)b * kNP + (s - 1)) * kD + d];
    x[idx] = v + pos[s * kD + d];
}

// ---------------- fp32 -> bf16 casts ----------------
__global__ void cast_bf16(const float* __restrict__ in, u16* __restrict__ out, long n4) {
    long i = (long)blockIdx.x * 256 + threadIdx.x;
    if (i >= n4) return;
    float4 v = *(const float4*)(in + i * 4);
    *(ushort4*)(out + i * 4) = make_ushort4(f2bf(v.x), f2bf(v.y), f2bf(v.z), f2bf(v.w));
}
// two sources in one flat dispatch (R12-proven: ~80us for all-layer W1+W2)
__global__ void cast2_bf16(const float* __restrict__ in1, const float* __restrict__ in2,
                           u16* __restrict__ out1, u16* __restrict__ out2, long n4each) {
    long i = (long)blockIdx.x * 256 + threadIdx.x;
    if (i >= 2 * n4each) return;
    const float* in = (i < n4each) ? in1 : in2;
    u16* out        = (i < n4each) ? out1 : out2;
    long j          = (i < n4each) ? i : i - n4each;
    float4 v = *(const float4*)(in + j * 4);
    *(ushort4*)(out + j * 4) = make_ushort4(f2bf(v.x), f2bf(v.y), f2bf(v.z), f2bf(v.w));
}

__global__ void zero_u16(u16* __restrict__ p, long n) {
    long i = (long)blockIdx.x * 256 + threadIdx.x;
    if (i < n) p[i] = 0;
}

// ---------------- per-head QKV weights, ALL layers: [L][12][192][64] bf16 + bias [L][12][192] ----------------
__global__ void build_whb_all(const float* __restrict__ Wq, const float* __restrict__ Wk,
                              const float* __restrict__ Wv, const float* __restrict__ bq,
                              const float* __restrict__ bk, const float* __restrict__ bv,
                              u16* __restrict__ Wh, float* __restrict__ bh) {
    int idx = blockIdx.x * 256 + threadIdx.x;
    if (idx >= kL * kNH * 192 * 64) return;
    int d  = idx & 63;
    int r  = (idx >> 6) % 192;
    int lh = (idx >> 6) / 192;         // l*12 + h
    int sec = r >> 6, e = r & 63;
    const float* W = (sec == 0) ? Wq : (sec == 1) ? Wk : Wv;
    Wh[idx] = f2bf(W[((long)lh * 64 + e) * 64 + d]);
    if (d == 0) {
        const float* bs = (sec == 0) ? bq : (sec == 1) ? bk : bv;
        bh[lh * 192 + r] = bs[lh * 64 + e];
    }
}

// ---------------- layernorm: one WAVE per token (4 tokens/block, no LDS) ----------------
__global__ __launch_bounds__(256) void vit_ln(const float* __restrict__ x,
                                              const float* __restrict__ g,
                                              const float* __restrict__ b,
                                              u16* __restrict__ out) {
    const int wave = threadIdx.x >> 6, lane = threadIdx.x & 63;
    const long t = (long)blockIdx.x * 4 + wave;
    const float* xr = x + t * kD;
    float4 v[3];
    float s = 0.0f, sq = 0.0f;
    #pragma unroll
    for (int k = 0; k < 3; k++) {
        v[k] = *(const float4*)(xr + (lane << 2) + k * 256);
        s  += v[k].x + v[k].y + v[k].z + v[k].w;
        sq += v[k].x * v[k].x + v[k].y * v[k].y + v[k].z * v[k].z + v[k].w * v[k].w;
    }
    #pragma unroll
    for (int o = 32; o; o >>= 1) { s += __shfl_xor(s, o); sq += __shfl_xor(sq, o); }
    const float mu  = s * (1.0f / kD);
    const float var = sq * (1.0f / kD) - mu * mu;
    const float rs  = rsqrtf(var + 1e-5f);
    u16* orow = out + t * kD;
    #pragma unroll
    for (int k = 0; k < 3; k++) {
        const int c = (lane << 2) + k * 256;
        const float4 gv = *(const float4*)(g + c);
        const float4 bv = *(const float4*)(b + c);
        ushort4 o4;
        o4.x = f2bf((v[k].x - mu) * rs * gv.x + bv.x);
        o4.y = f2bf((v[k].y - mu) * rs * gv.y + bv.y);
        o4.z = f2bf((v[k].z - mu) * rs * gv.z + bv.z);
        o4.w = f2bf((v[k].w - mu) * rs * gv.w + bv.w);
        *(ushort4*)(orow + c) = o4;
    }
}

// ---------------- bf16 MFMA GEMM, 128x128 tile (R5-proven loop: ~71us FF) ----------------
// BK=32, 3-deep LDS ring, counted vmcnt(4), TWO raw barriers/step, stage issued
// between fragment ds_reads and MFMAs. Source-side XOR chunk swizzle (0 conflicts).
// EPI: 0 bias->f32, 1 bias+gelu->bf16, 2 bias+residual(X)->f32, 3 bias->bf16
template <int EPI>
__global__ __launch_bounds__(256) void mm_bt(const u16* __restrict__ A, int lda,
                                             const u16* __restrict__ B, int ldb,
                                             const float* __restrict__ bias,
                                             const float* X, void* Cout, int ldc, int K) {
    __shared__ __align__(16) u16 As[3][4096];
    __shared__ __align__(16) u16 Bs[3][4096];

    const int gx = gridDim.x, gy = gridDim.y;
    const int nwg = gx * gy;
    const int disp = blockIdx.y * gx + blockIdx.x;
    const int q8 = nwg >> 3, r8 = nwg & 7;
    const int xcd = disp & 7, lot = disp >> 3;
    const int work = (xcd < r8 ? xcd * (q8 + 1) : r8 * (q8 + 1) + (xcd - r8) * q8) + lot;
    const int row0 = (work / gy) << 7;
    const int col0 = (work % gy) << 7;

    const int tid  = threadIdx.x;
    const int lane = tid & 63;
    const int wm = ((tid >> 6) >> 1) << 6;   // wave row 0/64
    const int wn = ((tid >> 6) & 1) << 6;    // wave col 0/64
    const int lr = lane & 15, lhi = lane >> 4;

    const int srow = tid >> 2;
    const int sch  = (((tid & 3) ^ ((srow >> 1) & 3)) << 3);
    const u16* Ag = A + (long)(row0 + srow) * lda + sch;
    const u16* Bg = B + (long)(col0 + srow) * ldb + sch;
    const long Astep = 64L * lda, Bstep = 64L * ldb;
    const int ldst = tid << 3;

    auto stage = [&](int buf, int k0) {
        cp16_async(&As[buf][ldst],        Ag + k0);
        cp16_async(&As[buf][ldst + 2048], Ag + Astep + k0);
        cp16_async(&Bs[buf][ldst],        Bg + k0);
        cp16_async(&Bs[buf][ldst + 2048], Bg + Bstep + k0);
    };
    stage(0, 0);
    stage(1, 32);

    f32x4 acc[4][4] = {};
    const int nk = K >> 5;
    const int rch = (lhi ^ ((lr >> 1) & 3)) << 3;
    int cur = 0;
    for (int t = 0; t < nk; t++) {
        if (t + 1 < nk) asm volatile("s_waitcnt vmcnt(4)" ::: "memory");
        else            asm volatile("s_waitcnt vmcnt(0)" ::: "memory");
        __builtin_amdgcn_sched_barrier(0);
        __builtin_amdgcn_s_barrier();
        bf16x8 af[4], bfr[4];
        #pragma unroll
        for (int m = 0; m < 4; m++)
            af[m] = *(const bf16x8*)&As[cur][(wm + (m << 4) + lr) * 32 + rch];
        #pragma unroll
        for (int n = 0; n < 4; n++)
            bfr[n] = *(const bf16x8*)&Bs[cur][(wn + (n << 4) + lr) * 32 + rch];
        if (t + 2 < nk) {
            int nb = cur + 2; if (nb >= 3) nb -= 3;
            stage(nb, (t + 2) << 5);
        }
        #pragma unroll
        for (int m = 0; m < 4; m++)
            #pragma unroll
            for (int n = 0; n < 4; n++)
                acc[m][n] = __builtin_amdgcn_mfma_f32_16x16x32_bf16(af[m], bfr[n], acc[m][n], 0, 0, 0);
        __builtin_amdgcn_s_barrier();
        cur = (cur + 1 == 3) ? 0 : cur + 1;
    }

    const int r0 = wm + (lhi << 2);
    const int cb = wn + lr;
    #pragma unroll
    for (int n = 0; n < 4; n++) {
        const int cc = col0 + cb + (n << 4);
        const float bv = bias[cc];
        #pragma unroll
        for (int m = 0; m < 4; m++) {
            #pragma unroll
            for (int r = 0; r < 4; r++) {
                const long idx = (long)(row0 + r0 + (m << 4) + r) * ldc + cc;
                float v = acc[m][n][r] + bv;
                if (EPI == 1) {
                    ((u16*)Cout)[idx] = f2bf(gelu_f(v));
                } else if (EPI == 2) {
                    ((float*)Cout)[idx] = v + X[idx];
                } else if (EPI == 3) {
                    ((u16*)Cout)[idx] = f2bf(v);
                } else {
                    ((float*)Cout)[idx] = v;
                }
            }
        }
    }
}

// ---------------- per-head block-diag QKV: qkv = h_head @ Wh^T + bh ----------------
__global__ __launch_bounds__(256) void mm_qkv(const u16* __restrict__ hbm,
                                              const u16* __restrict__ Wh,
                                              const float* __restrict__ bh,
                                              u16* __restrict__ qkv) {
    const int h = blockIdx.y;
    const int row0 = blockIdx.x << 6;
    const int tid = threadIdx.x, lane = tid & 63, wave = tid >> 6;
    const int l15 = lane & 15, lhi = lane >> 4;
    const u16* Ab = hbm + h * kDH + (lhi << 3);
    const u16* Bb = Wh + (long)h * 192 * 64 + (lhi << 3);

    bf16x8 af[4][2];
    #pragma unroll
    for (int m = 0; m < 4; m++) {
        const u16* ap = Ab + (long)(row0 + (m << 4) + l15) * kD;
        af[m][0] = *(const bf16x8*)ap;
        af[m][1] = *(const bf16x8*)(ap + 32);
    }
    bf16x8 bfr[3][2];
    #pragma unroll
    for (int n = 0; n < 3; n++) {
        const u16* bp = Bb + (long)(wave * 48 + (n << 4) + l15) * 64;
        bfr[n][0] = *(const bf16x8*)bp;
        bfr[n][1] = *(const bf16x8*)(bp + 32);
    }
    f32x4 acc[4][3] = {};
    __builtin_amdgcn_s_setprio(1);
    #pragma unroll
    for (int m = 0; m < 4; m++)
        #pragma unroll
        for (int n = 0; n < 3; n++) {
            acc[m][n] = __builtin_amdgcn_mfma_f32_16x16x32_bf16(af[m][0], bfr[n][0], acc[m][n], 0, 0, 0);
            acc[m][n] = __builtin_amdgcn_mfma_f32_16x16x32_bf16(af[m][1], bfr[n][1], acc[m][n], 0, 0, 0);
        }
    __builtin_amdgcn_s_setprio(0);
    #pragma unroll
    for (int n = 0; n < 3; n++) {
        const int c = wave * 48 + (n << 4) + l15;        // [0,192)
        const int sec = c >> 6, e = c & 63;
        const float bv = bh[h * 192 + c];
        const long gcol = (long)sec * kD + h * kDH + e;
        #pragma unroll
        for (int m = 0; m < 4; m++)
            #pragma unroll
            for (int i = 0; i < 4; i++) {
                const int r = row0 + (m << 4) + (lhi << 2) + i;
                qkv[(long)r * kQKV + gcol] = f2bf(acc[m][n][i] + bv);
            }
    }
}

// ---------------- fused attention: scores+softmax+PV, bf16 MFMA ----------------
__global__ __launch_bounds__(256) void vit_attn_fused(const u16* __restrict__ qkv,
                                                      float* __restrict__ x) {
    constexpr int SP = 224;
    constexpr int NT = 13;
    constexpr int LDP = 232;
    __shared__ u16 Plds[64][LDP];
    __shared__ u16 Vt[64][LDP];

    const int z = blockIdx.y, qt = blockIdx.x;
    const int b = z / kNH, h = z % kNH;
    const u16* base = qkv + (long)b * kS * kQKV;
    const u16* Qg = base + h * kDH;
    const u16* Kg = base + kD + h * kDH;
    const u16* Vg = base + 2 * kD + h * kDH;
    const int tid = threadIdx.x, lane = tid & 63, wave = tid >> 6;
    const int l15 = lane & 15, lhi = lane >> 4;

    for (int i = tid; i < (SP * kDH) / 4; i += 256) {
        int s  = i >> 4;
        int d0 = (i & 15) << 2;
        ushort4 v = *(const ushort4*)(Vg + (long)s * kQKV + d0);
        Vt[d0 + 0][s] = v.x; Vt[d0 + 1][s] = v.y;
        Vt[d0 + 2][s] = v.z; Vt[d0 + 3][s] = v.w;
    }

    const int qrow = (qt << 6) + (wave << 4) + l15;
    const u16* qrp = Qg + (long)qrow * kQKV + (lhi << 3);
    const bf16x8 qf0 = *(const bf16x8*)(qrp);
    const bf16x8 qf1 = *(const bf16x8*)(qrp + 32);

    f32x4 sc[NT];
    const u16* krp = Kg + (long)l15 * kQKV + (lhi << 3);
    __builtin_amdgcn_s_setprio(1);
    #pragma unroll
    for (int t = 0; t < NT; t++) {
        const u16* kp = krp + (long)(t << 4) * kQKV;
        bf16x8 kb0 = *(const bf16x8*)(kp);
        bf16x8 kb1 = *(const bf16x8*)(kp + 32);
        f32x4 a = {0.0f, 0.0f, 0.0f, 0.0f};
        a = __builtin_amdgcn_mfma_f32_16x16x32_bf16(qf0, kb0, a, 0, 0, 0);
        a = __builtin_amdgcn_mfma_f32_16x16x32_bf16(qf1, kb1, a, 0, 0, 0);
        sc[t] = a;
    }
    __builtin_amdgcn_s_setprio(0);

    float mx[4] = {-1e30f, -1e30f, -1e30f, -1e30f};
    #pragma unroll
    for (int t = 0; t < NT; t++) {
        const int c = (t << 4) + l15;
        #pragma unroll
        for (int q = 0; q < 4; q++) {
            float v = (c < kS) ? sc[t][q] * 0.125f : -1e30f;
            sc[t][q] = v;
            mx[q] = fmaxf(mx[q], v);
        }
    }
    #pragma unroll
    for (int o = 1; o < 16; o <<= 1)
        #pragma unroll
        for (int q = 0; q < 4; q++) mx[q] = fmaxf(mx[q], __shfl_xor(mx[q], o));
    float sum[4] = {0.0f, 0.0f, 0.0f, 0.0f};
    #pragma unroll
    for (int t = 0; t < NT; t++)
        #pragma unroll
        for (int q = 0; q < 4; q++) {
            float e = __expf(sc[t][q] - mx[q]);
            sc[t][q] = e;
            sum[q] += e;
        }
    #pragma unroll
    for (int o = 1; o < 16; o <<= 1)
        #pragma unroll
        for (int q = 0; q < 4; q++) sum[q] += __shfl_xor(sum[q], o);

    const int prow = (wave << 4) + (lhi << 2);
    #pragma unroll
    for (int t = 0; t < NT; t++)
        #pragma unroll
        for (int q = 0; q < 4; q++)
            Plds[prow + q][(t << 4) + l15] = f2bf(sc[t][q]);
    #pragma unroll
    for (int q = 0; q < 4; q++)
        Plds[prow + q][208 + l15] = 0;
    __syncthreads();

    f32x4 oacc[4] = {};
    const int arow = (wave << 4) + l15;
    const int koff = lhi << 3;
    __builtin_amdgcn_s_setprio(1);
    #pragma unroll
    for (int ks = 0; ks < 7; ks++) {
        bf16x8 pa = *(const bf16x8*)&Plds[arow][ks * 32 + koff];
        #pragma unroll
        for (int n = 0; n < 4; n++) {
            bf16x8 vb = *(const bf16x8*)&Vt[(n << 4) + l15][ks * 32 + koff];
            oacc[n] = __builtin_amdgcn_mfma_f32_16x16x32_bf16(pa, vb, oacc[n], 0, 0, 0);
        }
    }
    __builtin_amdgcn_s_setprio(0);

    const int orow0 = (qt << 6) + (wave << 4) + (lhi << 2);
    #pragma unroll
    for (int q = 0; q < 4; q++) {
        const int r = orow0 + q;
        if (r >= kS) continue;
        const float rinv = 1.0f / sum[q];
        float* xp = x + ((long)b * kS + r) * kD + h * kDH + l15;
        #pragma unroll
        for (int n = 0; n < 4; n++)
            xp[n << 4] += oacc[n][q] * rinv;
    }
}

// ---------------- fp32 GEMM (kept for tiny logits GEMM) ----------------
template <int ACT, int RES>
__global__ __launch_bounds__(256) void vit_gemm(const float* __restrict__ A, long lda, long sAz,
                                                const float* __restrict__ B, long ldb, long sBz,
                                                const float* __restrict__ bias, long sbz,
                                                const float* __restrict__ R,
                                                float* __restrict__ C, long ldc, long sCz,
                                                int M, int N, int K) {
    __shared__ __align__(16) float As[16][64];
    __shared__ __align__(16) float Bs[16][64];
    long z = blockIdx.z;
    A += z * sAz;  B += z * sBz;  C += z * sCz;
    if (bias) bias += z * sbz;
    const float* Rp = nullptr;
    if (RES) Rp = R + z * sCz;

    int row0 = blockIdx.x * 64, col0 = blockIdx.y * 64;
    int tid = threadIdx.x;
    int lr = tid >> 2, lk = (tid & 3) << 2;
    int tm = tid >> 4, tn = tid & 15;
    float acc[4][4] = {};

    for (int k0 = 0; k0 < K; k0 += 16) {
        float4 a = {0, 0, 0, 0}, bb = {0, 0, 0, 0};
        int gr = row0 + lr;
        if (gr < M) a = *(const float4*)(A + (long)gr * lda + k0 + lk);
        int gc = col0 + lr;
        if (gc < N) bb = *(const float4*)(B + (long)gc * ldb + k0 + lk);
        __syncthreads();
        As[lk + 0][lr] = a.x;  As[lk + 1][lr] = a.y;  As[lk + 2][lr] = a.z;  As[lk + 3][lr] = a.w;
        Bs[lk + 0][lr] = bb.x; Bs[lk + 1][lr] = bb.y; Bs[lk + 2][lr] = bb.z; Bs[lk + 3][lr] = bb.w;
        __syncthreads();
        #pragma unroll
        for (int k = 0; k < 16; k++) {
            const float4 av = *reinterpret_cast<const float4*>(&As[k][tm << 2]);
            const float4 bv = *reinterpret_cast<const float4*>(&Bs[k][tn << 2]);
            float aa[4] = {av.x, av.y, av.z, av.w};
            float bw[4] = {bv.x, bv.y, bv.z, bv.w};
            #pragma unroll
            for (int i = 0; i < 4; i++)
                #pragma unroll
                for (int j = 0; j < 4; j++)
                    acc[i][j] = fmaf(aa[i], bw[j], acc[i][j]);
        }
    }
    #pragma unroll
    for (int i = 0; i < 4; i++) {
        int r = row0 + (tm << 2) + i;
        if (r >= M) continue;
        #pragma unroll
        for (int j = 0; j < 4; j++) {
            int c = col0 + (tn << 2) + j;
            if (c >= N) continue;
            float v = acc[i][j];
            if (bias) v += bias[c];
            if (ACT == 1) v = gelu_f(v);
            if (RES) v += Rp[(long)r * ldc + c];
            C[(long)r * ldc + c] = v;
        }
    }
}

// ---------------- final softmax over 1000 logits ----------------
__global__ __launch_bounds__(256) void vit_smout(const float* __restrict__ logits,
                                                 float* __restrict__ out) {
    int b = blockIdx.x;
    const float* p = logits + (long)b * kOUT;
    int tid = threadIdx.x;
    float v[4];
    float mx = -1e30f;
    #pragma unroll
    for (int i = 0; i < 4; i++) {
        int c = tid + (i << 8);
        v[i] = (c < kOUT) ? p[c] : -1e30f;
        mx = fmaxf(mx, v[i]);
    }
    #pragma unroll
    for (int o = 32; o; o >>= 1) mx = fmaxf(mx, __shfl_xor(mx, o));
    __shared__ float red[8];
    int wid = tid >> 6, lane = tid & 63;
    if (lane == 0) red[wid] = mx;
    __syncthreads();
    mx = fmaxf(fmaxf(red[0], red[1]), fmaxf(red[2], red[3]));
    float sum = 0.0f;
    #pragma unroll
    for (int i = 0; i < 4; i++) {
        int c = tid + (i << 8);
        if (c < kOUT) { v[i] = expf(v[i] - mx); sum += v[i]; }
    }
    #pragma unroll
    for (int o = 32; o; o >>= 1) sum += __shfl_xor(sum, o);
    __syncthreads();
    if (lane == 0) red[4 + wid] = sum;
    __syncthreads();
    sum = red[4] + red[5] + red[6] + red[7];
    float inv = 1.0f / sum;
    #pragma unroll
    for (int i = 0; i < 4; i++) {
        int c = tid + (i << 8);
        if (c < kOUT) out[(long)b * kOUT + c] = v[i] * inv;
    }
}

// ---------------- host driver ----------------
extern "C" void kernel_launch(void* const* d_in, const int* in_sizes, int n_in,
                              void* d_out, int out_size, void* d_ws, size_t ws_size,
                              hipStream_t stream) {
    (void)in_sizes; (void)n_in; (void)out_size;
    const float* images  = (const float*)d_in[0];
    const float* W_patch = (const float*)d_in[1];
    const float* b_patch = (const float*)d_in[2];
    const float* cls     = (const float*)d_in[3];
    const float* ln1_g   = (const float*)d_in[4];
    const float* ln1_b   = (const float*)d_in[5];
    const float* Wq      = (const float*)d_in[6];
    const float* bq      = (const float*)d_in[7];
    const float* Wk      = (const float*)d_in[8];
    const float* bk      = (const float*)d_in[9];
    const float* Wv      = (const float*)d_in[10];
    const float* bv      = (const float*)d_in[11];
    const float* ln2_g   = (const float*)d_in[12];
    const float* ln2_b   = (const float*)d_in[13];
    const float* W1      = (const float*)d_in[14];
    const float* b1      = (const float*)d_in[15];
    const float* W2      = (const float*)d_in[16];
    const float* b2      = (const float*)d_in[17];
    const float* Wo      = (const float*)d_in[18];
    const float* bo      = (const float*)d_in[19];

    char* wsB = (char*)d_ws;
    auto alloc = [&](size_t bytes) { char* p = wsB; wsB += (bytes + 255) & ~(size_t)255; return p; };
    float* pos    = (float*)alloc((size_t)kS * kD * 4);
    float* x      = (float*)alloc((size_t)kMP * kD * 4);
    u16*   hb     = (u16*)  alloc((size_t)kMP * kD * 2);
    u16*   qkvb   = (u16*)  alloc((size_t)kMP * kQKV * 2);
    u16*   ff1b   = (u16*)  alloc((size_t)kMP * kFF * 2);
    u16*   Whb    = (u16*)  alloc((size_t)kL * kNH * 192 * 64 * 2);  // all layers
    u16*   Wpb    = (u16*)  alloc((size_t)kD * kD * 2);
    float* bhb    = (float*)alloc((size_t)kL * kNH * 192 * 4);
    float* logits = (float*)alloc((size_t)kB * kOUT * 4);

    // W1/W2 bf16: hoist all layers into ws if it fits, else per-layer double-use buffer
    const size_t perW  = (size_t)kFF * kD;                 // elems per W matrix
    const size_t used  = (size_t)(wsB - (char*)d_ws);
    const bool   hoist = ws_size >= used + 2 * kL * perW * 2 + (1u << 20);
    u16* W12b = (u16*)alloc(hoist ? 2 * kL * perW * 2 : 2 * perW * 2);

    float* tokens   = (float*)qkvb;   // reuse (pre-loop only)
    u16*   patchesb = ff1b;           // reuse (pre-loop only)

    // ---- pre-loop ----
    vit_posenc<<<(kS * kD + 255) / 256, 256, 0, stream>>>(pos);
    vit_im2col_bf16<<<(int)(((long)kMP * kD) / 256), 256, 0, stream>>>(images, patchesb);
    cast_bf16<<<(kD * kD / 4 + 255) / 256, 256, 0, stream>>>(W_patch, Wpb, (long)kD * kD / 4);
    build_whb_all<<<(kL * kNH * 192 * 64 + 255) / 256, 256, 0, stream>>>(
        Wq, Wk, Wv, bq, bk, bv, Whb, bhb);
    zero_u16<<<(96 * kD + 255) / 256, 256, 0, stream>>>(hb + (long)kTOK * kD, 96L * kD);
    if (hoist)   // all 12 layers' W1 then all W2, one flat dispatch
        cast2_bf16<<<(int)((2 * kL * perW / 4 + 255) / 256), 256, 0, stream>>>(
            W1, W2, W12b, W12b + kL * perW, (long)kL * perW / 4);
    mm_bt<0><<<dim3(kMP / 128, kD / 128), 256, 0, stream>>>(
        patchesb, kD, Wpb, kD, b_patch, nullptr, tokens, kD, kD);
    vit_assemble<<<(int)(((long)kMP * kD) / 256), 256, 0, stream>>>(tokens, cls, pos, x);

    for (int l = 0; l < kL; l++) {
        u16* W1l = hoist ? (W12b + (size_t)l * perW)            : W12b;
        u16* W2l = hoist ? (W12b + (size_t)(kL + l) * perW)     : W12b + perW;
        if (!hoist)
            cast2_bf16<<<(int)((2 * perW / 4 + 255) / 256), 256, 0, stream>>>(
                W1 + (size_t)l * perW, W2 + (size_t)l * perW, W1l, W2l, (long)perW / 4);

        vit_ln<<<kTOK / 4, 256, 0, stream>>>(x, ln1_g + (long)l * kD, ln1_b + (long)l * kD, hb);
        mm_qkv<<<dim3(kMP / 64, kNH), 256, 0, stream>>>(
            hb, Whb + (long)l * kNH * 192 * 64, bhb + (long)l * kNH * 192, qkvb);

        vit_attn_fused<<<dim3(4, kB * kNH), 256, 0, stream>>>(qkvb, x);

        vit_ln<<<kTOK / 4, 256, 0, stream>>>(x, ln2_g + (long)l * kD, ln2_b + (long)l * kD, hb);
        mm_bt<1><<<dim3(kMP / 128, kFF / 128), 256, 0, stream>>>(
            hb, kD, W1l, kD, b1 + (long)l * kFF, nullptr, ff1b, kFF, kD);
        mm_bt<2><<<dim3(kMP / 128, kD / 128), 256, 0, stream>>>(
            ff1b, kFF, W2l, kFF, b2 + (long)l * kD, x, x, kD, kFF);
    }

    vit_gemm<0, 0><<<dim3(1, 16, 1), 256, 0, stream>>>(
        x, (long)kS * kD, 0, Wo, kD, 0, bo, 0, nullptr,
        logits, kOUT, 0, kB, kOUT, kD);
    vit_smout<<<kB, 256, 0, stream>>>(logits, (float*)d_out);
}

// Round 15
// 2501.099 us; speedup vs baseline: 1.0566x; 1.0044x over previous
//
#include <hip/hip_runtime.h>
#include <math.h>

// ---------------- constants (ViT-Base on 224x224) ----------------
static constexpr int kB   = 32;
static constexpr int kC   = 3;
static constexpr int kH   = 224;
static constexpr int kW   = 224;
static constexpr int kP   = 14;    // patches per side
static constexpr int kPS  = 16;    // patch size
static constexpr int kD   = 768;
static constexpr int kNH  = 12;
static constexpr int kDH  = 64;
static constexpr int kL   = 12;
static constexpr int kFF  = 3072;
static constexpr int kOUT = 1000;
static constexpr int kS   = 197;   // tokens
static constexpr int kTOK = kB * kS;    // 6304
static constexpr int kNP  = kP * kP;    // 196
static constexpr int kMP  = 6400;       // padded token rows (50*128)
static constexpr int kQKV = 3 * kD;     // 2304

typedef unsigned short u16;
typedef __attribute__((ext_vector_type(4))) float f32x4;
typedef __attribute__((ext_vector_type(8))) short bf16x8;

__device__ __forceinline__ u16 f2bf(float x) {
    unsigned u = __float_as_uint(x);
    return (u16)((u + 0x7FFFu + ((u >> 16) & 1u)) >> 16);   // RNE
}
__device__ __forceinline__ float bf2f(u16 x) {
    return __uint_as_float((unsigned)x << 16);
}
__device__ __forceinline__ void cp16_async(void* lds, const void* g) {
    __builtin_amdgcn_global_load_lds((const __attribute__((address_space(1))) unsigned*)g,
                                     (__attribute__((address_space(3))) unsigned*)lds,
                                     16, 0, 0);
}
// exact-gelu via Abramowitz-Stegun 7.1.26 erf (max abs err 1.5e-7; ~8 VALU + rcp + exp)
__device__ __forceinline__ float gelu_f(float v) {
    float z = v * 0.70710678118654752f;
    float s = fabsf(z);
    float t = 1.0f / (1.0f + 0.3275911f * s);
    float p = t * (0.254829592f + t * (-0.284496736f +
              t * (1.421413741f + t * (-1.453152027f + t * 1.061405429f))));
    float e = p * __expf(-s * s);
    float erfv = (z < 0.0f) ? (e - 1.0f) : (1.0f - e);
    return 0.5f * v * (1.0f + erfv);
}

// ---------------- positional encoding (float math) ----------------
__global__ void vit_posenc(float* __restrict__ pos) {
    int idx = blockIdx.x * 256 + threadIdx.x;
    if (idx >= kS * kD) return;
    int s = idx / kD, d = idx % kD;
    int je = d & ~1;
    float ang = (float)s * __expf((float)je * (-9.210340371976184f / 768.0f));
    pos[idx] = (d & 1) ? cosf(ang) : sinf(ang);
}

// ---------------- im2col -> bf16 patches [6400][768], pad rows zero ----------------
__global__ void vit_im2col_bf16(const float* __restrict__ img, u16* __restrict__ patches) {
    long idx = (long)blockIdx.x * 256 + threadIdx.x;
    if (idx >= (long)kMP * kD) return;
    int col = (int)(idx % kD);
    long rp = idx / kD;
    if (rp >= (long)kB * kNP) { patches[idx] = 0; return; }
    int p = (int)(rp % kNP), b = (int)(rp / kNP);
    int c = col >> 8;
    int rem = col & 255;
    int i = rem >> 4, j = rem & 15;
    int py = p / kP, px = p % kP;
    patches[idx] = f2bf(img[(((long)b * kC + c) * kH + py * kPS + i) * kW + px * kPS + j]);
}

// ---------------- assemble x = concat(cls, tokens) + pos; pad rows zero ----------------
__global__ void vit_assemble(const float* __restrict__ tokens, const float* __restrict__ cls,
                             const float* __restrict__ pos, float* __restrict__ x) {
    long idx = (long)blockIdx.x * 256 + threadIdx.x;
    if (idx >= (long)kMP * kD) return;
    int d = (int)(idx % kD);
    long bs = idx / kD;
    if (bs >= kTOK) { x[idx] = 0.0f; return; }
    int s = (int)(bs % kS);
    long b = bs / kS;
    float v = (s == 0) ? cls[d] : tokens[((long)b * kNP + (s - 1)) * kD + d];
    x[idx] = v + pos[s * kD + d];
}

// ---------------- fp32 -> bf16 casts ----------------
__global__ void cast_bf16(const float* __restrict__ in, u16* __restrict__ out, long n4) {
    long i = (long)blockIdx.x * 256 + threadIdx.x;
    if (i >= n4) return;
    float4 v = *(const float4*)(in + i * 4);
    *(ushort4*)(out + i * 4) = make_ushort4(f2bf(v.x), f2bf(v.y), f2bf(v.z), f2bf(v.w));
}
// two sources, 8 elems/thread: 2x float4 reads, one 16B bf16x8 store (full coalescing)
__global__ void cast2_bf16(const float* __restrict__ in1, const float* __restrict__ in2,
                           u16* __restrict__ out1, u16* __restrict__ out2, long n8each) {
    long i = (long)blockIdx.x * 256 + threadIdx.x;
    if (i >= 2 * n8each) return;
    const float* in = (i < n8each) ? in1 : in2;
    u16* out        = (i < n8each) ? out1 : out2;
    long j          = (i < n8each) ? i : i - n8each;
    float4 a = *(const float4*)(in + j * 8);
    float4 b = *(const float4*)(in + j * 8 + 4);
    bf16x8 o;
    o[0] = (short)f2bf(a.x); o[1] = (short)f2bf(a.y);
    o[2] = (short)f2bf(a.z); o[3] = (short)f2bf(a.w);
    o[4] = (short)f2bf(b.x); o[5] = (short)f2bf(b.y);
    o[6] = (short)f2bf(b.z); o[7] = (short)f2bf(b.w);
    *(bf16x8*)(out + j * 8) = o;
}

__global__ void zero_u16(u16* __restrict__ p, long n) {
    long i = (long)blockIdx.x * 256 + threadIdx.x;
    if (i < n) p[i] = 0;
}

// ---------------- per-head QKV weights, ALL layers: [L][12][192][64] bf16 + bias [L][12][192] ----------------
__global__ void build_whb_all(const float* __restrict__ Wq, const float* __restrict__ Wk,
                              const float* __restrict__ Wv, const float* __restrict__ bq,
                              const float* __restrict__ bk, const float* __restrict__ bv,
                              u16* __restrict__ Wh, float* __restrict__ bh) {
    int idx = blockIdx.x * 256 + threadIdx.x;
    if (idx >= kL * kNH * 192 * 64) return;
    int d  = idx & 63;
    int r  = (idx >> 6) % 192;
    int lh = (idx >> 6) / 192;         // l*12 + h
    int sec = r >> 6, e = r & 63;
    const float* W = (sec == 0) ? Wq : (sec == 1) ? Wk : Wv;
    Wh[idx] = f2bf(W[((long)lh * 64 + e) * 64 + d]);
    if (d == 0) {
        const float* bs = (sec == 0) ? bq : (sec == 1) ? bk : bv;
        bh[lh * 192 + r] = bs[lh * 64 + e];
    }
}

// ---------------- layernorm: one WAVE per token (4 tokens/block, no LDS) ----------------
__global__ __launch_bounds__(256) void vit_ln(const float* __restrict__ x,
                                              const float* __restrict__ g,
                                              const float* __restrict__ b,
                                              u16* __restrict__ out) {
    const int wave = threadIdx.x >> 6, lane = threadIdx.x & 63;
    const long t = (long)blockIdx.x * 4 + wave;
    const float* xr = x + t * kD;
    float4 v[3];
    float s = 0.0f, sq = 0.0f;
    #pragma unroll
    for (int k = 0; k < 3; k++) {
        v[k] = *(const float4*)(xr + (lane << 2) + k * 256);
        s  += v[k].x + v[k].y + v[k].z + v[k].w;
        sq += v[k].x * v[k].x + v[k].y * v[k].y + v[k].z * v[k].z + v[k].w * v[k].w;
    }
    #pragma unroll
    for (int o = 32; o; o >>= 1) { s += __shfl_xor(s, o); sq += __shfl_xor(sq, o); }
    const float mu  = s * (1.0f / kD);
    const float var = sq * (1.0f / kD) - mu * mu;
    const float rs  = rsqrtf(var + 1e-5f);
    u16* orow = out + t * kD;
    #pragma unroll
    for (int k = 0; k < 3; k++) {
        const int c = (lane << 2) + k * 256;
        const float4 gv = *(const float4*)(g + c);
        const float4 bv = *(const float4*)(b + c);
        ushort4 o4;
        o4.x = f2bf((v[k].x - mu) * rs * gv.x + bv.x);
        o4.y = f2bf((v[k].y - mu) * rs * gv.y + bv.y);
        o4.z = f2bf((v[k].z - mu) * rs * gv.z + bv.z);
        o4.w = f2bf((v[k].w - mu) * rs * gv.w + bv.w);
        *(ushort4*)(orow + c) = o4;
    }
}

// ---------------- bf16 MFMA GEMM, 128x128 tile (R5-proven loop: ~71us FF) ----------------
// BK=32, 3-deep LDS ring, counted vmcnt(4), TWO raw barriers/step, stage issued
// between fragment ds_reads and MFMAs. Source-side XOR chunk swizzle (0 conflicts).
// EPI: 0 bias->f32, 1 bias+gelu->bf16, 2 bias+residual(X)->f32, 3 bias->bf16
template <int EPI>
__global__ __launch_bounds__(256) void mm_bt(const u16* __restrict__ A, int lda,
                                             const u16* __restrict__ B, int ldb,
                                             const float* __restrict__ bias,
                                             const float* X, void* Cout, int ldc, int K) {
    __shared__ __align__(16) u16 As[3][4096];
    __shared__ __align__(16) u16 Bs[3][4096];

    const int gx = gridDim.x, gy = gridDim.y;
    const int nwg = gx * gy;
    const int disp = blockIdx.y * gx + blockIdx.x;
    const int q8 = nwg >> 3, r8 = nwg & 7;
    const int xcd = disp & 7, lot = disp >> 3;
    const int work = (xcd < r8 ? xcd * (q8 + 1) : r8 * (q8 + 1) + (xcd - r8) * q8) + lot;
    const int row0 = (work / gy) << 7;
    const int col0 = (work % gy) << 7;

    const int tid  = threadIdx.x;
    const int lane = tid & 63;
    const int wm = ((tid >> 6) >> 1) << 6;   // wave row 0/64
    const int wn = ((tid >> 6) & 1) << 6;    // wave col 0/64
    const int lr = lane & 15, lhi = lane >> 4;

    const int srow = tid >> 2;
    const int sch  = (((tid & 3) ^ ((srow >> 1) & 3)) << 3);
    const u16* Ag = A + (long)(row0 + srow) * lda + sch;
    const u16* Bg = B + (long)(col0 + srow) * ldb + sch;
    const long Astep = 64L * lda, Bstep = 64L * ldb;
    const int ldst = tid << 3;

    auto stage = [&](int buf, int k0) {
        cp16_async(&As[buf][ldst],        Ag + k0);
        cp16_async(&As[buf][ldst + 2048], Ag + Astep + k0);
        cp16_async(&Bs[buf][ldst],        Bg + k0);
        cp16_async(&Bs[buf][ldst + 2048], Bg + Bstep + k0);
    };
    stage(0, 0);
    stage(1, 32);

    f32x4 acc[4][4] = {};
    const int nk = K >> 5;
    const int rch = (lhi ^ ((lr >> 1) & 3)) << 3;
    int cur = 0;
    for (int t = 0; t < nk; t++) {
        if (t + 1 < nk) asm volatile("s_waitcnt vmcnt(4)" ::: "memory");
        else            asm volatile("s_waitcnt vmcnt(0)" ::: "memory");
        __builtin_amdgcn_sched_barrier(0);
        __builtin_amdgcn_s_barrier();
        bf16x8 af[4], bfr[4];
        #pragma unroll
        for (int m = 0; m < 4; m++)
            af[m] = *(const bf16x8*)&As[cur][(wm + (m << 4) + lr) * 32 + rch];
        #pragma unroll
        for (int n = 0; n < 4; n++)
            bfr[n] = *(const bf16x8*)&Bs[cur][(wn + (n << 4) + lr) * 32 + rch];
        if (t + 2 < nk) {
            int nb = cur + 2; if (nb >= 3) nb -= 3;
            stage(nb, (t + 2) << 5);
        }
        #pragma unroll
        for (int m = 0; m < 4; m++)
            #pragma unroll
            for (int n = 0; n < 4; n++)
                acc[m][n] = __builtin_amdgcn_mfma_f32_16x16x32_bf16(af[m], bfr[n], acc[m][n], 0, 0, 0);
        __builtin_amdgcn_s_barrier();
        cur = (cur + 1 == 3) ? 0 : cur + 1;
    }

    const int r0 = wm + (lhi << 2);
    const int cb = wn + lr;
    #pragma unroll
    for (int n = 0; n < 4; n++) {
        const int cc = col0 + cb + (n << 4);
        const float bv = bias[cc];
        #pragma unroll
        for (int m = 0; m < 4; m++) {
            #pragma unroll
            for (int r = 0; r < 4; r++) {
                const long idx = (long)(row0 + r0 + (m << 4) + r) * ldc + cc;
                float v = acc[m][n][r] + bv;
                if (EPI == 1) {
                    ((u16*)Cout)[idx] = f2bf(gelu_f(v));
                } else if (EPI == 2) {
                    ((float*)Cout)[idx] = v + X[idx];
                } else if (EPI == 3) {
                    ((u16*)Cout)[idx] = f2bf(v);
                } else {
                    ((float*)Cout)[idx] = v;
                }
            }
        }
    }
}

// ---------------- per-head block-diag QKV: qkv = h_head @ Wh^T + bh ----------------
__global__ __launch_bounds__(256) void mm_qkv(const u16* __restrict__ hbm,
                                              const u16* __restrict__ Wh,
                                              const float* __restrict__ bh,
                                              u16* __restrict__ qkv) {
    const int h = blockIdx.y;
    const int row0 = blockIdx.x << 6;
    const int tid = threadIdx.x, lane = tid & 63, wave = tid >> 6;
    const int l15 = lane & 15, lhi = lane >> 4;
    const u16* Ab = hbm + h * kDH + (lhi << 3);
    const u16* Bb = Wh + (long)h * 192 * 64 + (lhi << 3);

    bf16x8 af[4][2];
    #pragma unroll
    for (int m = 0; m < 4; m++) {
        const u16* ap = Ab + (long)(row0 + (m << 4) + l15) * kD;
        af[m][0] = *(const bf16x8*)ap;
        af[m][1] = *(const bf16x8*)(ap + 32);
    }
    bf16x8 bfr[3][2];
    #pragma unroll
    for (int n = 0; n < 3; n++) {
        const u16* bp = Bb + (long)(wave * 48 + (n << 4) + l15) * 64;
        bfr[n][0] = *(const bf16x8*)bp;
        bfr[n][1] = *(const bf16x8*)(bp + 32);
    }
    f32x4 acc[4][3] = {};
    __builtin_amdgcn_s_setprio(1);
    #pragma unroll
    for (int m = 0; m < 4; m++)
        #pragma unroll
        for (int n = 0; n < 3; n++) {
            acc[m][n] = __builtin_amdgcn_mfma_f32_16x16x32_bf16(af[m][0], bfr[n][0], acc[m][n], 0, 0, 0);
            acc[m][n] = __builtin_amdgcn_mfma_f32_16x16x32_bf16(af[m][1], bfr[n][1], acc[m][n], 0, 0, 0);
        }
    __builtin_amdgcn_s_setprio(0);
    #pragma unroll
    for (int n = 0; n < 3; n++) {
        const int c = wave * 48 + (n << 4) + l15;        // [0,192)
        const int sec = c >> 6, e = c & 63;
        const float bv = bh[h * 192 + c];
        const long gcol = (long)sec * kD + h * kDH + e;
        #pragma unroll
        for (int m = 0; m < 4; m++)
            #pragma unroll
            for (int i = 0; i < 4; i++) {
                const int r = row0 + (m << 4) + (lhi << 2) + i;
                qkv[(long)r * kQKV + gcol] = f2bf(acc[m][n][i] + bv);
            }
    }
}

// ---------------- fused attention: scores+softmax+PV, bf16 MFMA ----------------
// V-staging issued AFTER the QK^T loop: vmcnt is FIFO, so K-frag waits would
// otherwise drain all V loads too; V latency now hides under softmax VALU.
__global__ __launch_bounds__(256) void vit_attn_fused(const u16* __restrict__ qkv,
                                                      float* __restrict__ x) {
    constexpr int SP = 224;
    constexpr int NT = 13;
    constexpr int LDP = 232;
    __shared__ u16 Plds[64][LDP];
    __shared__ u16 Vt[64][LDP];

    const int z = blockIdx.y, qt = blockIdx.x;
    const int b = z / kNH, h = z % kNH;
    const u16* base = qkv + (long)b * kS * kQKV;
    const u16* Qg = base + h * kDH;
    const u16* Kg = base + kD + h * kDH;
    const u16* Vg = base + 2 * kD + h * kDH;
    const int tid = threadIdx.x, lane = tid & 63, wave = tid >> 6;
    const int l15 = lane & 15, lhi = lane >> 4;

    // ---- Q fragments + QK^T first (critical path) ----
    const int qrow = (qt << 6) + (wave << 4) + l15;
    const u16* qrp = Qg + (long)qrow * kQKV + (lhi << 3);
    const bf16x8 qf0 = *(const bf16x8*)(qrp);
    const bf16x8 qf1 = *(const bf16x8*)(qrp + 32);

    f32x4 sc[NT];
    const u16* krp = Kg + (long)l15 * kQKV + (lhi << 3);
    __builtin_amdgcn_s_setprio(1);
    #pragma unroll
    for (int t = 0; t < NT; t++) {
        const u16* kp = krp + (long)(t << 4) * kQKV;
        bf16x8 kb0 = *(const bf16x8*)(kp);
        bf16x8 kb1 = *(const bf16x8*)(kp + 32);
        f32x4 a = {0.0f, 0.0f, 0.0f, 0.0f};
        a = __builtin_amdgcn_mfma_f32_16x16x32_bf16(qf0, kb0, a, 0, 0, 0);
        a = __builtin_amdgcn_mfma_f32_16x16x32_bf16(qf1, kb1, a, 0, 0, 0);
        sc[t] = a;
    }
    __builtin_amdgcn_s_setprio(0);

    // ---- stage V transposed (latency hides under softmax below) ----
    for (int i = tid; i < (SP * kDH) / 4; i += 256) {
        int s  = i >> 4;
        int d0 = (i & 15) << 2;
        ushort4 v = *(const ushort4*)(Vg + (long)s * kQKV + d0);
        Vt[d0 + 0][s] = v.x; Vt[d0 + 1][s] = v.y;
        Vt[d0 + 2][s] = v.z; Vt[d0 + 3][s] = v.w;
    }

    // ---- softmax in registers ----
    float mx[4] = {-1e30f, -1e30f, -1e30f, -1e30f};
    #pragma unroll
    for (int t = 0; t < NT; t++) {
        const int c = (t << 4) + l15;
        #pragma unroll
        for (int q = 0; q < 4; q++) {
            float v = (c < kS) ? sc[t][q] * 0.125f : -1e30f;
            sc[t][q] = v;
            mx[q] = fmaxf(mx[q], v);
        }
    }
    #pragma unroll
    for (int o = 1; o < 16; o <<= 1)
        #pragma unroll
        for (int q = 0; q < 4; q++) mx[q] = fmaxf(mx[q], __shfl_xor(mx[q], o));
    float sum[4] = {0.0f, 0.0f, 0.0f, 0.0f};
    #pragma unroll
    for (int t = 0; t < NT; t++)
        #pragma unroll
        for (int q = 0; q < 4; q++) {
            float e = __expf(sc[t][q] - mx[q]);
            sc[t][q] = e;
            sum[q] += e;
        }
    #pragma unroll
    for (int o = 1; o < 16; o <<= 1)
        #pragma unroll
        for (int q = 0; q < 4; q++) sum[q] += __shfl_xor(sum[q], o);

    const int prow = (wave << 4) + (lhi << 2);
    #pragma unroll
    for (int t = 0; t < NT; t++)
        #pragma unroll
        for (int q = 0; q < 4; q++)
            Plds[prow + q][(t << 4) + l15] = f2bf(sc[t][q]);
    #pragma unroll
    for (int q = 0; q < 4; q++)
        Plds[prow + q][208 + l15] = 0;
    __syncthreads();   // orders V staging + P writes before LDS reads

    f32x4 oacc[4] = {};
    const int arow = (wave << 4) + l15;
    const int koff = lhi << 3;
    __builtin_amdgcn_s_setprio(1);
    #pragma unroll
    for (int ks = 0; ks < 7; ks++) {
        bf16x8 pa = *(const bf16x8*)&Plds[arow][ks * 32 + koff];
        #pragma unroll
        for (int n = 0; n < 4; n++) {
            bf16x8 vb = *(const bf16x8*)&Vt[(n << 4) + l15][ks * 32 + koff];
            oacc[n] = __builtin_amdgcn_mfma_f32_16x16x32_bf16(pa, vb, oacc[n], 0, 0, 0);
        }
    }
    __builtin_amdgcn_s_setprio(0);

    const int orow0 = (qt << 6) + (wave << 4) + (lhi << 2);
    #pragma unroll
    for (int q = 0; q < 4; q++) {
        const int r = orow0 + q;
        if (r >= kS) continue;
        const float rinv = 1.0f / sum[q];
        float* xp = x + ((long)b * kS + r) * kD + h * kDH + l15;
        #pragma unroll
        for (int n = 0; n < 4; n++)
            xp[n << 4] += oacc[n][q] * rinv;
    }
}

// ---------------- fp32 GEMM (kept for tiny logits GEMM) ----------------
template <int ACT, int RES>
__global__ __launch_bounds__(256) void vit_gemm(const float* __restrict__ A, long lda, long sAz,
                                                const float* __restrict__ B, long ldb, long sBz,
                                                const float* __restrict__ bias, long sbz,
                                                const float* __restrict__ R,
                                                float* __restrict__ C, long ldc, long sCz,
                                                int M, int N, int K) {
    __shared__ __align__(16) float As[16][64];
    __shared__ __align__(16) float Bs[16][64];
    long z = blockIdx.z;
    A += z * sAz;  B += z * sBz;  C += z * sCz;
    if (bias) bias += z * sbz;
    const float* Rp = nullptr;
    if (RES) Rp = R + z * sCz;

    int row0 = blockIdx.x * 64, col0 = blockIdx.y * 64;
    int tid = threadIdx.x;
    int lr = tid >> 2, lk = (tid & 3) << 2;
    int tm = tid >> 4, tn = tid & 15;
    float acc[4][4] = {};

    for (int k0 = 0; k0 < K; k0 += 16) {
        float4 a = {0, 0, 0, 0}, bb = {0, 0, 0, 0};
        int gr = row0 + lr;
        if (gr < M) a = *(const float4*)(A + (long)gr * lda + k0 + lk);
        int gc = col0 + lr;
        if (gc < N) bb = *(const float4*)(B + (long)gc * ldb + k0 + lk);
        __syncthreads();
        As[lk + 0][lr] = a.x;  As[lk + 1][lr] = a.y;  As[lk + 2][lr] = a.z;  As[lk + 3][lr] = a.w;
        Bs[lk + 0][lr] = bb.x; Bs[lk + 1][lr] = bb.y; Bs[lk + 2][lr] = bb.z; Bs[lk + 3][lr] = bb.w;
        __syncthreads();
        #pragma unroll
        for (int k = 0; k < 16; k++) {
            const float4 av = *reinterpret_cast<const float4*>(&As[k][tm << 2]);
            const float4 bv = *reinterpret_cast<const float4*>(&Bs[k][tn << 2]);
            float aa[4] = {av.x, av.y, av.z, av.w};
            float bw[4] = {bv.x, bv.y, bv.z, bv.w};
            #pragma unroll
            for (int i = 0; i < 4; i++)
                #pragma unroll
                for (int j = 0; j < 4; j++)
                    acc[i][j] = fmaf(aa[i], bw[j], acc[i][j]);
        }
    }
    #pragma unroll
    for (int i = 0; i < 4; i++) {
        int r = row0 + (tm << 2) + i;
        if (r >= M) continue;
        #pragma unroll
        for (int j = 0; j < 4; j++) {
            int c = col0 + (tn << 2) + j;
            if (c >= N) continue;
            float v = acc[i][j];
            if (bias) v += bias[c];
            if (ACT == 1) v = gelu_f(v);
            if (RES) v += Rp[(long)r * ldc + c];
            C[(long)r * ldc + c] = v;
        }
    }
}

// ---------------- final softmax over 1000 logits ----------------
__global__ __launch_bounds__(256) void vit_smout(const float* __restrict__ logits,
                                                 float* __restrict__ out) {
    int b = blockIdx.x;
    const float* p = logits + (long)b * kOUT;
    int tid = threadIdx.x;
    float v[4];
    float mx = -1e30f;
    #pragma unroll
    for (int i = 0; i < 4; i++) {
        int c = tid + (i << 8);
        v[i] = (c < kOUT) ? p[c] : -1e30f;
        mx = fmaxf(mx, v[i]);
    }
    #pragma unroll
    for (int o = 32; o; o >>= 1) mx = fmaxf(mx, __shfl_xor(mx, o));
    __shared__ float red[8];
    int wid = tid >> 6, lane = tid & 63;
    if (lane == 0) red[wid] = mx;
    __syncthreads();
    mx = fmaxf(fmaxf(red[0], red[1]), fmaxf(red[2], red[3]));
    float sum = 0.0f;
    #pragma unroll
    for (int i = 0; i < 4; i++) {
        int c = tid + (i << 8);
        if (c < kOUT) { v[i] = expf(v[i] - mx); sum += v[i]; }
    }
    #pragma unroll
    for (int o = 32; o; o >>= 1) sum += __shfl_xor(sum, o);
    __syncthreads();
    if (lane == 0) red[4 + wid] = sum;
    __syncthreads();
    sum = red[4] + red[5] + red[6] + red[7];
    float inv = 1.0f / sum;
    #pragma unroll
    for (int i = 0; i < 4; i++) {
        int c = tid + (i << 8);
        if (c < kOUT) out[(long)b * kOUT + c] = v[i] * inv;
    }
}

// ---------------- host driver ----------------
extern "C" void kernel_launch(void* const* d_in, const int* in_sizes, int n_in,
                              void* d_out, int out_size, void* d_ws, size_t ws_size,
                              hipStream_t stream) {
    (void)in_sizes; (void)n_in; (void)out_size;
    const float* images  = (const float*)d_in[0];
    const float* W_patch = (const float*)d_in[1];
    const float* b_patch = (const float*)d_in[2];
    const float* cls     = (const float*)d_in[3];
    const float* ln1_g   = (const float*)d_in[4];
    const float* ln1_b   = (const float*)d_in[5];
    const float* Wq      = (const float*)d_in[6];
    const float* bq      = (const float*)d_in[7];
    const float* Wk      = (const float*)d_in[8];
    const float* bk      = (const float*)d_in[9];
    const float* Wv      = (const float*)d_in[10];
    const float* bv      = (const float*)d_in[11];
    const float* ln2_g   = (const float*)d_in[12];
    const float* ln2_b   = (const float*)d_in[13];
    const float* W1      = (const float*)d_in[14];
    const float* b1      = (const float*)d_in[15];
    const float* W2      = (const float*)d_in[16];
    const float* b2      = (const float*)d_in[17];
    const float* Wo      = (const float*)d_in[18];
    const float* bo      = (const float*)d_in[19];

    char* wsB = (char*)d_ws;
    auto alloc = [&](size_t bytes) { char* p = wsB; wsB += (bytes + 255) & ~(size_t)255; return p; };
    float* pos    = (float*)alloc((size_t)kS * kD * 4);
    float* x      = (float*)alloc((size_t)kMP * kD * 4);
    u16*   hb     = (u16*)  alloc((size_t)kMP * kD * 2);
    u16*   qkvb   = (u16*)  alloc((size_t)kMP * kQKV * 2);
    u16*   ff1b   = (u16*)  alloc((size_t)kMP * kFF * 2);
    u16*   Whb    = (u16*)  alloc((size_t)kL * kNH * 192 * 64 * 2);  // all layers
    u16*   Wpb    = (u16*)  alloc((size_t)kD * kD * 2);
    float* bhb    = (float*)alloc((size_t)kL * kNH * 192 * 4);
    float* logits = (float*)alloc((size_t)kB * kOUT * 4);

    // W1/W2 bf16: hoist all layers into ws if it fits, else per-layer double-use buffer
    const size_t perW  = (size_t)kFF * kD;                 // elems per W matrix
    const size_t used  = (size_t)(wsB - (char*)d_ws);
    const bool   hoist = ws_size >= used + 2 * kL * perW * 2 + (1u << 20);
    u16* W12b = (u16*)alloc(hoist ? 2 * kL * perW * 2 : 2 * perW * 2);

    float* tokens   = (float*)qkvb;   // reuse (pre-loop only)
    u16*   patchesb = ff1b;           // reuse (pre-loop only)

    // ---- pre-loop ----
    vit_posenc<<<(kS * kD + 255) / 256, 256, 0, stream>>>(pos);
    vit_im2col_bf16<<<(int)(((long)kMP * kD) / 256), 256, 0, stream>>>(images, patchesb);
    cast_bf16<<<(kD * kD / 4 + 255) / 256, 256, 0, stream>>>(W_patch, Wpb, (long)kD * kD / 4);
    build_whb_all<<<(kL * kNH * 192 * 64 + 255) / 256, 256, 0, stream>>>(
        Wq, Wk, Wv, bq, bk, bv, Whb, bhb);
    zero_u16<<<(96 * kD + 255) / 256, 256, 0, stream>>>(hb + (long)kTOK * kD, 96L * kD);
    if (hoist)   // all 12 layers' W1 then all W2, one flat dispatch (8 elems/thread)
        cast2_bf16<<<(int)((2 * kL * perW / 8 + 255) / 256), 256, 0, stream>>>(
            W1, W2, W12b, W12b + kL * perW, (long)kL * perW / 8);
    mm_bt<0><<<dim3(kMP / 128, kD / 128), 256, 0, stream>>>(
        patchesb, kD, Wpb, kD, b_patch, nullptr, tokens, kD, kD);
    vit_assemble<<<(int)(((long)kMP * kD) / 256), 256, 0, stream>>>(tokens, cls, pos, x);

    for (int l = 0; l < kL; l++) {
        u16* W1l = hoist ? (W12b + (size_t)l * perW)            : W12b;
        u16* W2l = hoist ? (W12b + (size_t)(kL + l) * perW)     : W12b + perW;
        if (!hoist)
            cast2_bf16<<<(int)((2 * perW / 8 + 255) / 256), 256, 0, stream>>>(
                W1 + (size_t)l * perW, W2 + (size_t)l * perW, W1l, W2l, (long)perW / 8);

        vit_ln<<<kTOK / 4, 256, 0, stream>>>(x, ln1_g + (long)l * kD, ln1_b + (long)l * kD, hb);
        mm_qkv<<<dim3(kMP / 64, kNH), 256, 0, stream>>>(
            hb, Whb + (long)l * kNH * 192 * 64, bhb + (long)l * kNH * 192, qkvb);

        vit_attn_fused<<<dim3(4, kB * kNH), 256, 0, stream>>>(qkvb, x);

        vit_ln<<<kTOK / 4, 256, 0, stream>>>(x, ln2_g + (long)l * kD, ln2_b + (long)l * kD, hb);
        mm_bt<1><<<dim3(kMP / 128, kFF / 128), 256, 0, stream>>>(
            hb, kD, W1l, kD, b1 + (long)l * kFF, nullptr, ff1b, kFF, kD);
        mm_bt<2><<<dim3(kMP / 128, kD / 128), 256, 0, stream>>>(
            ff1b, kFF, W2l, kFF, b2 + (long)l * kD, x, x, kD, kFF);
    }

    vit_gemm<0, 0><<<dim3(1, 16, 1), 256, 0, stream>>>(
        x, (long)kS * kD, 0, Wo, kD, 0, bo, 0, nullptr,
        logits, kOUT, 0, kB, kOUT, kD);
    vit_smout<<<kB, 256, 0, stream>>>(logits, (float*)d_out);
}